// Round 4
// baseline (530.745 us; speedup 1.0000x reference)
//
#include <hip/hip_runtime.h>

typedef unsigned short ushort_t;
typedef unsigned int   uint_t;
typedef __bf16 bf16x8 __attribute__((ext_vector_type(8)));
typedef float  f32x4  __attribute__((ext_vector_type(8/2)));

typedef __attribute__((address_space(3))) void lds_void_t;
typedef __attribute__((address_space(1))) void gbl_void_t;

#define NN 8192
#define HH 128
#define KS 8          // K-split factor
#define KLEN 1024     // K per split slice
#define NT 32         // K-tiles per block (KLEN / 32)

__device__ __forceinline__ ushort_t f2bf(float x) {
    uint_t u = __float_as_uint(x);
    u += 0x7fffu + ((u >> 16) & 1u);          // RNE; inputs are finite
    return (ushort_t)(u >> 16);
}
__device__ __forceinline__ float bf2f(uint_t lo16) { return __uint_as_float(lo16 << 16); }
__device__ __forceinline__ float leaky(float x) { return x > 0.f ? x : 0.01f * x; }

// ---------------------------------------------------------------------------
// K0: adj f32 -> bf16 (RNE) + row sums -> s_i = rsqrt(r_i+1), rinv_i = 1/r_i
__global__ __launch_bounds__(256) void conv_rowsum(const float* __restrict__ adj,
    ushort_t* __restrict__ adjb, float* __restrict__ s, float* __restrict__ rinv)
{
    const int i = blockIdx.x;
    const float4* arow = (const float4*)(adj + ((size_t)i << 13));
    uint2* brow = (uint2*)(adjb + ((size_t)i << 13));
    float partial = 0.f;
    for (int t = threadIdx.x; t < 2048; t += 256) {
        const float4 v = arow[t];
        partial += (v.x + v.y) + (v.z + v.w);
        uint2 o;
        o.x = (uint_t)f2bf(v.x) | ((uint_t)f2bf(v.y) << 16);
        o.y = (uint_t)f2bf(v.z) | ((uint_t)f2bf(v.w) << 16);
        brow[t] = o;
    }
    #pragma unroll
    for (int off = 32; off; off >>= 1) partial += __shfl_xor(partial, off);
    __shared__ float ps[4];
    if ((threadIdx.x & 63) == 0) ps[threadIdx.x >> 6] = partial;
    __syncthreads();
    if (threadIdx.x == 0) {
        const float tot = (ps[0] + ps[1]) + (ps[2] + ps[3]);
        s[i]    = rsqrtf(tot + 1.0f);
        rinv[i] = 1.0f / tot;
    }
}

// ---------------------------------------------------------------------------
// K2: build Bt [256][8192] bf16.  Bt[c][j] = c<128 ? s_j*u[j][c] : rinv_j*v[j][c-128]
// u==nullptr (level 4): zero-fill c<128 so the BN=256 GEMM stays one template.
__global__ __launch_bounds__(256) void prescale(const float* __restrict__ u,
    const float* __restrict__ v, const float* __restrict__ s, const float* __restrict__ rinv,
    ushort_t* __restrict__ Bt)
{
    const int j0 = (blockIdx.x & 127) << 6;
    const int c0 = (blockIdx.x >> 7) << 6;
    __shared__ float tile[64][65];
    const int tx = threadIdx.x & 63;
    const int ty = threadIdx.x >> 6;
    #pragma unroll
    for (int rr = 0; rr < 16; ++rr) {
        const int jl = ty + (rr << 2);
        const int j = j0 + jl;
        const int c = c0 + tx;
        float val;
        if (c < 128) val = u ? s[j] * u[((size_t)j << 7) + c] : 0.f;
        else         val = rinv[j] * v[((size_t)j << 7) + (c - 128)];
        tile[jl][tx] = val;
    }
    __syncthreads();
    #pragma unroll
    for (int rr = 0; rr < 16; ++rr) {
        const int cl = ty + (rr << 2);
        Bt[((size_t)(c0 + cl) << 13) + j0 + tx] = f2bf(tile[tx][cl]);
    }
}

// ---------------------------------------------------------------------------
// K3: Yb[ks][8192][256] (bf16) = adjb[256-row panel] @ Bt^T slice (bf16 MFMA)
// Ring GEMM: BM=BN=256, BK=32, 8 waves (2Mx4N, 128x64 each), 4-deep LDS ring.
// LDS swizzle: physical 16B slot s at row r holds logical k-group fk = s ^ ((r>>1)&3).
//   - stage: linear LDS dest, source k-offset pre-swizzled (lane-only: (l&3)^((l>>3)&3))
//   - read:  slot = fk ^ ((frow>>1)&3)  -> 8 consecutive rows cover all 8 bank
//     groups -> 2-way (free).  Tail iterations peeled with exact vmcnt immediates.
#define WAITB(S) do {                                         \
    asm volatile("s_waitcnt " S ::: "memory");                \
    __builtin_amdgcn_sched_barrier(0);                        \
    __builtin_amdgcn_s_barrier();                             \
    __builtin_amdgcn_sched_barrier(0);                        \
} while (0)

template<int REP>
__global__ __launch_bounds__(512, 2) void gemm_adj(const ushort_t* __restrict__ A,
    const ushort_t* __restrict__ Bt, ushort_t* __restrict__ Yb)
{
    __shared__ ushort_t lds[4 * 16384];   // ring: [4][A 8192 | B 8192] ushorts
    const int bid = blockIdx.x;
    const int mb = bid & 31;
    const int ks = bid >> 5;
    const size_t mBase = (size_t)mb * 256;
    const int tid = threadIdx.x;
    const int w = tid >> 6, l = tid & 63;
    const int wr = w >> 2, wc = w & 3;     // wave tile: rows wr*128, cols wc*64
    const int frow = l & 15, fk = l >> 4;  // fragment row/col, logical k-slot
    const int rsw = (frow >> 1) & 3;       // read-side swizzle (lane const)
    const int srow = l >> 2;               // staging row-in-16
    const int skoff = (((l & 3) ^ ((l >> 3) & 3)) << 3);   // pre-swizzled src k-off
    const int kBeg = ks << 10;

    f32x4 acc[8][4] = {};

    auto STAGE = [&](int t) {
        const int k0 = kBeg + (t << 5);
        ushort_t* base = &lds[(t & 3) << 14];
        #pragma unroll
        for (int q = 0; q < 2; ++q) {
            const int c = (w << 1) + q;              // 0..15 wave-uniform chunk
            const int row = (c << 4) + srow;
            __builtin_amdgcn_global_load_lds(
                (const gbl_void_t*)(A + ((mBase + row) << 13) + k0 + skoff),
                (lds_void_t*)(base + (c << 9)), 16, 0, 0);
            __builtin_amdgcn_global_load_lds(
                (const gbl_void_t*)(Bt + ((size_t)row << 13) + k0 + skoff),
                (lds_void_t*)(base + 8192 + (c << 9)), 16, 0, 0);
        }
    };

    auto COMPUTE = [&](int T) {
        const ushort_t* buf = &lds[(T & 3) << 14];
        bf16x8 av[8], bv[4];
        #pragma unroll
        for (int mi = 0; mi < 8; ++mi) {
            const int row = (wr << 7) + (mi << 4) + frow;
            av[mi] = *(const bf16x8*)(buf + (row << 5) + ((fk ^ rsw) << 3));
        }
        #pragma unroll
        for (int ni = 0; ni < 4; ++ni) {
            const int col = (wc << 6) + (ni << 4) + frow;
            bv[ni] = *(const bf16x8*)(buf + 8192 + (col << 5) + ((fk ^ rsw) << 3));
        }
        __builtin_amdgcn_s_setprio(1);
        #pragma unroll
        for (int mi = 0; mi < 8; ++mi)
            #pragma unroll
            for (int ni = 0; ni < 4; ++ni)
                acc[mi][ni] = __builtin_amdgcn_mfma_f32_16x16x32_bf16(
                    av[mi], bv[ni], acc[mi][ni], 0, 0, 0);
        __builtin_amdgcn_s_setprio(0);
    };

    for (int rep = 0; rep < REP; ++rep) {
        STAGE(0); STAGE(1); STAGE(2);
        for (int T = 0; T < NT - 3; ++T) {
            WAITB("vmcnt(8)");          // tile T landed; T+1,T+2 in flight
            STAGE(T + 3);
            COMPUTE(T);
        }
        WAITB("vmcnt(8)"); COMPUTE(NT - 3);
        WAITB("vmcnt(4)"); COMPUTE(NT - 2);
        WAITB("vmcnt(0)"); COMPUTE(NT - 1);
    }
    __syncthreads();   // full drain before LDS reuse

    // Epilogue: acc -> LDS bf16 [256][256] -> coalesced 16B stores.
    // C/D layout (m89-verified): col = lane&15, row = (lane>>4)*4 + reg
    ushort_t* Cs = lds;
    const int orow = (l >> 4) << 2;
    const int ocol = l & 15;
    #pragma unroll
    for (int mi = 0; mi < 8; ++mi) {
        #pragma unroll
        for (int ni = 0; ni < 4; ++ni) {
            const int rl = (wr << 7) + (mi << 4) + orow;
            const int cl = (wc << 6) + (ni << 4) + ocol;
            #pragma unroll
            for (int r = 0; r < 4; ++r)
                Cs[(rl + r) * 256 + cl] = f2bf(acc[mi][ni][r]);
        }
    }
    __syncthreads();
    const size_t sliceBase = ((size_t)ks * NN + mBase) * 256;
    #pragma unroll
    for (int p = 0; p < 16; ++p) {
        const int idx16 = (p << 9) + tid;    // 0..8191 16B-chunks
        const int row   = idx16 >> 5;
        const int c16   = idx16 & 31;
        const uint4 v = *(const uint4*)(&Cs[(row << 8) + (c16 << 3)]);
        *(uint4*)(Yb + sliceBase + (size_t)row * 256 + (c16 << 3)) = v;
    }
}

// ---------------------------------------------------------------------------
// K4: sum KS bf16 partials + postscale.
//   c<128:  hA_out = s_i*Y + s_i^2*u   (A_norm@u with self-loop diagonal)
//   c>=128: px_out = 0.5*(v + Y)       (lazy walk P)
__global__ __launch_bounds__(256) void reduce_post(const ushort_t* __restrict__ Yb,
    const float* __restrict__ u, const float* __restrict__ v, const float* __restrict__ s,
    float4* __restrict__ hA_out, float4* __restrict__ px_out)
{
    const size_t idx = (size_t)blockIdx.x * 256 + threadIdx.x;   // 0..524287
    const int i  = (int)(idx >> 6);
    const int c4 = (int)(idx & 63) << 2;
    if (c4 < 128 && hA_out == nullptr) return;
    const size_t SL = (size_t)NN * 256;   // ushorts per K-split slice
    const ushort_t* p = Yb + ((size_t)i << 8) + c4;
    float ex = 0.f, ey = 0.f, ez = 0.f, ew = 0.f;
    #pragma unroll
    for (int kss = 0; kss < KS; ++kss) {
        const uint2 q = *(const uint2*)(p + kss * SL);
        ex += bf2f(q.x & 0xffffu);
        ey += __uint_as_float(q.x & 0xffff0000u);
        ez += bf2f(q.y & 0xffffu);
        ew += __uint_as_float(q.y & 0xffff0000u);
    }
    if (c4 < 128) {
        const float si = s[i], si2 = si * si;
        const float4 uu = ((const float4*)u)[(size_t)i * 32 + (c4 >> 2)];
        float4 o;
        o.x = si * ex + si2 * uu.x;  o.y = si * ey + si2 * uu.y;
        o.z = si * ez + si2 * uu.z;  o.w = si * ew + si2 * uu.w;
        hA_out[(size_t)i * 32 + (c4 >> 2)] = o;
    } else {
        const float4 vv = ((const float4*)v)[(size_t)i * 32 + ((c4 - 128) >> 2)];
        float4 o;
        o.x = 0.5f * (vv.x + ex);  o.y = 0.5f * (vv.y + ey);
        o.z = 0.5f * (vv.z + ez);  o.w = 0.5f * (vv.w + ew);
        px_out[(size_t)i * 32 + ((c4 - 128) >> 2)] = o;
    }
}

// ---------------------------------------------------------------------------
// K5: 6-way attention fusion. One wave per node; 2 k's per lane.
// The relu(X)@a[0:128] term is constant across the 6 slots -> cancels in softmax.
__global__ __launch_bounds__(256) void fuse_attn(const float* __restrict__ X,
    const float* __restrict__ hA, const float* __restrict__ hA2, const float* __restrict__ hA3,
    const float* __restrict__ px, const float* __restrict__ p2x, const float* __restrict__ p4x,
    const float* __restrict__ a, float* __restrict__ hp)
{
    const int w = threadIdx.x >> 6, l = threadIdx.x & 63;
    const size_t i = (size_t)blockIdx.x * 4 + w;
    const size_t base = i << 7;
    float f[6][2];
    float e[6] = {0.f, 0.f, 0.f, 0.f, 0.f, 0.f};
    #pragma unroll
    for (int h = 0; h < 2; ++h) {
        const int k = l + (h << 6);
        const float a2 = a[128 + k];
        const float x   = X[base + k];
        const float t1  = leaky(hA [base + k]);
        const float t2  = leaky(hA2[base + k]);
        const float t3  = leaky(hA3[base + k]);
        const float pk  = px [base + k];
        const float p2k = p2x[base + k];
        const float p4k = p4x[base + k];
        const float s1 = fabsf(x - pk);
        const float s2 = fabsf(pk - p2k);
        const float s3 = fabsf(p2k - p4k);
        f[0][h] = t1; f[1][h] = t2; f[2][h] = t3;
        f[3][h] = s1; f[4][h] = s2; f[5][h] = s3;
        e[0] += fmaxf(t1, 0.f) * a2;
        e[1] += fmaxf(t2, 0.f) * a2;
        e[2] += fmaxf(t3, 0.f) * a2;
        e[3] += s1 * a2;                 // |.| >= 0, relu is identity
        e[4] += s2 * a2;
        e[5] += s3 * a2;
    }
    #pragma unroll
    for (int ss = 0; ss < 6; ++ss) {
        #pragma unroll
        for (int off = 32; off; off >>= 1) e[ss] += __shfl_xor(e[ss], off);
    }
    float mx = e[0];
    #pragma unroll
    for (int ss = 1; ss < 6; ++ss) mx = fmaxf(mx, e[ss]);
    float at[6], sum = 0.f;
    #pragma unroll
    for (int ss = 0; ss < 6; ++ss) { at[ss] = expf(e[ss] - mx); sum += at[ss]; }
    const float inv = 1.f / (6.f * sum);
    #pragma unroll
    for (int h = 0; h < 2; ++h) {
        float o = 0.f;
        #pragma unroll
        for (int ss = 0; ss < 6; ++ss) o += at[ss] * f[ss][h];
        hp[base + l + (h << 6)] = o * inv;
    }
}

// ---------------------------------------------------------------------------
// K6: out = leaky(Hm @ W^T + b), f32. W staged in LDS (stride 140).
__global__ __launch_bounds__(256) void mlp(const float* __restrict__ Hm,
    const float* __restrict__ W, const float* __restrict__ b, float* __restrict__ out)
{
    __shared__ float Ws[128 * 140];
    __shared__ float Hs[16 * 140];
    const int node0 = blockIdx.x << 4;
    for (int rr = 0; rr < 64; ++rr) {
        const int idx = rr * 256 + threadIdx.x;
        Ws[(idx >> 7) * 140 + (idx & 127)] = W[idx];
    }
    #pragma unroll
    for (int rr = 0; rr < 8; ++rr) {
        const int idx = rr * 256 + threadIdx.x;
        Hs[(idx >> 7) * 140 + (idx & 127)] = Hm[((size_t)node0 << 7) + idx];
    }
    __syncthreads();
    const int c = threadIdx.x & 15;
    const int n = threadIdx.x >> 4;
    float acc[8] = {};
    for (int k4 = 0; k4 < 32; ++k4) {
        const float4 h4 = *(const float4*)(&Hs[n * 140 + (k4 << 2)]);
        #pragma unroll
        for (int r = 0; r < 8; ++r) {
            const float4 w4 = *(const float4*)(&Ws[(c + (r << 4)) * 140 + (k4 << 2)]);
            acc[r] += h4.x * w4.x + h4.y * w4.y + h4.z * w4.z + h4.w * w4.w;
        }
    }
    const size_t obase = ((size_t)(node0 + n)) << 7;
    #pragma unroll
    for (int r = 0; r < 8; ++r) {
        const int o = c + (r << 4);
        out[obase + o] = leaky(acc[r] + b[o]);
    }
}

// ---------------------------------------------------------------------------
extern "C" void kernel_launch(void* const* d_in, const int* in_sizes, int n_in,
                              void* d_out, int out_size, void* d_ws, size_t ws_size,
                              hipStream_t stream)
{
    const float* X   = (const float*)d_in[0];
    const float* adj = (const float*)d_in[1];
    const float* W1  = (const float*)d_in[2];
    const float* b1  = (const float*)d_in[3];
    const float* W2  = (const float*)d_in[4];
    const float* b2  = (const float*)d_in[5];
    const float* a   = (const float*)d_in[6];
    float* out = (float*)d_out;

    // Workspace layout (~192.1 MB total)
    char* ws = (char*)d_ws;
    ushort_t* adjb = (ushort_t*)ws;                        // 128 MB
    ushort_t* Bt   = (ushort_t*)(ws + 134217728ull);       //   4 MB
    ushort_t* Yb   = (ushort_t*)(ws + 138412032ull);       //  32 MB (KS=8 bf16 partials)
    float* hA  = (float*)(ws + 171966464ull);              //   4 MB each below
    float* hA2 = hA  + 1048576;
    float* hA3 = hA2 + 1048576;
    float* px  = hA3 + 1048576;
    float* p2x = px  + 1048576;
    float* p3x = p2x + 1048576;
    float* p4x = p3x + 1048576;
    float* sbuf  = p4x + 1048576;                          // 32 KB
    float* rinvb = sbuf + 8192;                            // 32 KB
    float* hp   = (float*)Bt;   // overlay: Bt dead after L4 GEMM
    float* out1 = (float*)Yb;   // overlay: Yb dead after L4 reduce

    conv_rowsum<<<8192, 256, 0, stream>>>(adj, adjb, sbuf, rinvb);

    // Level 1: u=X (hop), v=X (walk)
    prescale   <<<512, 256, 0, stream>>>(X, X, sbuf, rinvb, Bt);
    gemm_adj<1><<<256, 512, 0, stream>>>(adjb, Bt, Yb);
    reduce_post<<<2048, 256, 0, stream>>>(Yb, X, X, sbuf,
                                          (float4*)hA, (float4*)px);
    // Level 2
    prescale   <<<512, 256, 0, stream>>>(hA, px, sbuf, rinvb, Bt);
    gemm_adj<1><<<256, 512, 0, stream>>>(adjb, Bt, Yb);
    reduce_post<<<2048, 256, 0, stream>>>(Yb, hA, px, sbuf,
                                          (float4*)hA2, (float4*)p2x);
    // Level 3
    prescale   <<<512, 256, 0, stream>>>(hA2, p2x, sbuf, rinvb, Bt);
    gemm_adj<1><<<256, 512, 0, stream>>>(adjb, Bt, Yb);
    reduce_post<<<2048, 256, 0, stream>>>(Yb, hA2, p2x, sbuf,
                                          (float4*)hA3, (float4*)p3x);
    // Level 4: walk only (zero-filled hop half of Bt)
    prescale   <<<512, 256, 0, stream>>>(nullptr, p3x, sbuf, rinvb, Bt);
    gemm_adj<1><<<256, 512, 0, stream>>>(adjb, Bt, Yb);
    reduce_post<<<2048, 256, 0, stream>>>(Yb, nullptr, p3x, sbuf,
                                          nullptr, (float4*)p4x);

    // DIAGNOSTIC (this round only): surface the GEMM in rocprof top-5.
    // Yb is dead here (reduce_post L4 consumed it; mlp rewrites out1 later).
    // Deterministic; costs ~8x one GEMM level of wall time.
    gemm_adj<8><<<256, 512, 0, stream>>>(adjb, Bt, Yb);

    fuse_attn<<<2048, 256, 0, stream>>>(X, hA, hA2, hA3, px, p2x, p4x, a, hp);
    mlp<<<512, 256, 0, stream>>>(hp, W1, b1, out1);
    mlp<<<512, 256, 0, stream>>>(out1, W2, b2, out);
}

// Round 5
// 304.854 us; speedup vs baseline: 1.7410x; 1.7410x over previous
//
#include <hip/hip_runtime.h>

typedef unsigned short ushort_t;
typedef unsigned int   uint_t;
typedef __bf16 bf16x8 __attribute__((ext_vector_type(8)));
typedef float  f32x4  __attribute__((ext_vector_type(8/2)));

typedef __attribute__((address_space(3))) void lds_void_t;
typedef __attribute__((address_space(1))) void gbl_void_t;

#define NN 8192
#define HH 128
#define KS 8          // K-split factor
#define KLEN 1024     // K per split slice
#define NT 32         // K-tiles per block (KLEN / 32)

__device__ __forceinline__ ushort_t f2bf(float x) {
    uint_t u = __float_as_uint(x);
    u += 0x7fffu + ((u >> 16) & 1u);          // RNE; inputs are finite
    return (ushort_t)(u >> 16);
}
__device__ __forceinline__ float bf2f(uint_t lo16) { return __uint_as_float(lo16 << 16); }
__device__ __forceinline__ float leaky(float x) { return x > 0.f ? x : 0.01f * x; }

// ---------------------------------------------------------------------------
// K0: adj f32 -> bf16 (RNE) + row sums -> s_i = rsqrt(r_i+1), rinv_i = 1/r_i
__global__ __launch_bounds__(256) void conv_rowsum(const float* __restrict__ adj,
    ushort_t* __restrict__ adjb, float* __restrict__ s, float* __restrict__ rinv)
{
    const int i = blockIdx.x;
    const float4* arow = (const float4*)(adj + ((size_t)i << 13));
    uint2* brow = (uint2*)(adjb + ((size_t)i << 13));
    float partial = 0.f;
    for (int t = threadIdx.x; t < 2048; t += 256) {
        const float4 v = arow[t];
        partial += (v.x + v.y) + (v.z + v.w);
        uint2 o;
        o.x = (uint_t)f2bf(v.x) | ((uint_t)f2bf(v.y) << 16);
        o.y = (uint_t)f2bf(v.z) | ((uint_t)f2bf(v.w) << 16);
        brow[t] = o;
    }
    #pragma unroll
    for (int off = 32; off; off >>= 1) partial += __shfl_xor(partial, off);
    __shared__ float ps[4];
    if ((threadIdx.x & 63) == 0) ps[threadIdx.x >> 6] = partial;
    __syncthreads();
    if (threadIdx.x == 0) {
        const float tot = (ps[0] + ps[1]) + (ps[2] + ps[3]);
        s[i]    = rsqrtf(tot + 1.0f);
        rinv[i] = 1.0f / tot;
    }
}

// ---------------------------------------------------------------------------
// K2: build Bt [256][8192] bf16 for level 1 (from X,X).
//   Bt[c][j] = c<128 ? s_j*u[j][c] : rinv_j*v[j][c-128]
__global__ __launch_bounds__(256) void prescale(const float* __restrict__ u,
    const float* __restrict__ v, const float* __restrict__ s, const float* __restrict__ rinv,
    ushort_t* __restrict__ Bt)
{
    const int j0 = (blockIdx.x & 127) << 6;
    const int c0 = (blockIdx.x >> 7) << 6;
    __shared__ float tile[64][65];
    const int tx = threadIdx.x & 63;
    const int ty = threadIdx.x >> 6;
    #pragma unroll
    for (int rr = 0; rr < 16; ++rr) {
        const int jl = ty + (rr << 2);
        const int j = j0 + jl;
        const int c = c0 + tx;
        float val;
        if (c < 128) val = s[j]    * u[((size_t)j << 7) + c];
        else         val = rinv[j] * v[((size_t)j << 7) + (c - 128)];
        tile[jl][tx] = val;
    }
    __syncthreads();
    #pragma unroll
    for (int rr = 0; rr < 16; ++rr) {
        const int cl = ty + (rr << 2);
        Bt[((size_t)(c0 + cl) << 13) + j0 + tx] = f2bf(tile[tx][cl]);
    }
}

// ---------------------------------------------------------------------------
// K3: Yb[ks][8192][256] (bf16) = adjb[256-row panel] @ Bt^T slice (bf16 MFMA)
// Ring GEMM, register-pipelined: BM=BN=256, BK=32, 8 waves (2Mx4N), 4-deep
// LDS ring. Iteration T: {vmcnt(4)+barrier; STAGE(T+3); ds_read bv(T),
// av(T+1); MFMA(T) from regs}. MFMAs consume LAST iteration's av set, so
// ds_read and MFMA are independent and interleave (LDS hides under MFMA).
// Hazards: buffer rewritten >=1 barrier after last consumed read (ds reads
// complete before their consuming MFMA, which precedes barrier arrival).
// LDS swizzle: slot s at row r holds k-group fk = s ^ ((r>>1)&3)  (2-way max).
#define WAITB(S) do {                                         \
    asm volatile("s_waitcnt " S ::: "memory");                \
    __builtin_amdgcn_sched_barrier(0);                        \
    __builtin_amdgcn_s_barrier();                             \
    __builtin_amdgcn_sched_barrier(0);                        \
} while (0)

__global__ __launch_bounds__(512, 2) void gemm_adj(const ushort_t* __restrict__ A,
    const ushort_t* __restrict__ Bt, ushort_t* __restrict__ Yb)
{
    __shared__ ushort_t lds[4 * 16384];   // ring: [4][A 8192 | B 8192] ushorts
    const int bid = blockIdx.x;
    const int mb = bid & 31;
    const int ks = bid >> 5;
    const size_t mBase = (size_t)mb * 256;
    const int tid = threadIdx.x;
    const int w = tid >> 6, l = tid & 63;
    const int wr = w >> 2, wc = w & 3;     // wave tile: rows wr*128, cols wc*64
    const int frow = l & 15, fk = l >> 4;  // fragment row/col, logical k-slot
    const int fsl = ((fk ^ ((frow >> 1) & 3)) << 3);       // swizzled frag offset
    const int srow = l >> 2;               // staging row-in-16
    const int skoff = (((l & 3) ^ ((l >> 3) & 3)) << 3);   // pre-swizzled src k-off
    const int kBeg = ks << 10;

    f32x4 acc[8][4] = {};
    bf16x8 avA[8], avB[8], bv[4];

    auto STAGE = [&](int t) {
        const int k0 = kBeg + (t << 5);
        ushort_t* base = &lds[(t & 3) << 14];
        #pragma unroll
        for (int q = 0; q < 2; ++q) {
            const int c = (w << 1) + q;              // 0..15 wave-uniform chunk
            const int row = (c << 4) + srow;
            __builtin_amdgcn_global_load_lds(
                (const gbl_void_t*)(A + ((mBase + row) << 13) + k0 + skoff),
                (lds_void_t*)(base + (c << 9)), 16, 0, 0);
            __builtin_amdgcn_global_load_lds(
                (const gbl_void_t*)(Bt + ((size_t)row << 13) + k0 + skoff),
                (lds_void_t*)(base + 8192 + (c << 9)), 16, 0, 0);
        }
    };
    auto READ_AV = [&](int t, bf16x8* av) {
        const ushort_t* buf = &lds[(t & 3) << 14];
        #pragma unroll
        for (int mi = 0; mi < 8; ++mi) {
            const int row = (wr << 7) + (mi << 4) + frow;
            av[mi] = *(const bf16x8*)(buf + (row << 5) + fsl);
        }
    };
    auto READ_BV = [&](int t) {
        const ushort_t* buf = &lds[(t & 3) << 14];
        #pragma unroll
        for (int ni = 0; ni < 4; ++ni) {
            const int col = (wc << 6) + (ni << 4) + frow;
            bv[ni] = *(const bf16x8*)(buf + 8192 + (col << 5) + fsl);
        }
    };
    auto MFMA = [&](const bf16x8* av) {
        __builtin_amdgcn_s_setprio(1);
        #pragma unroll
        for (int mi = 0; mi < 8; ++mi)
            #pragma unroll
            for (int ni = 0; ni < 4; ++ni)
                acc[mi][ni] = __builtin_amdgcn_mfma_f32_16x16x32_bf16(
                    av[mi], bv[ni], acc[mi][ni], 0, 0, 0);
        __builtin_amdgcn_s_setprio(0);
    };

    STAGE(0); STAGE(1); STAGE(2);          // 12 loads/wave outstanding
    WAITB("vmcnt(8)");                     // tile 0 landed
    READ_AV(0, avA);

    #pragma unroll 1
    for (int T = 0; T < NT - 4; T += 2) {
        WAITB("vmcnt(4)");                 // tile T+1 landed (T+2 in flight)
        STAGE(T + 3);
        READ_BV(T);  READ_AV(T + 1, avB);  MFMA(avA);
        WAITB("vmcnt(4)");                 // tile T+2 landed (T+3 in flight)
        STAGE(T + 4);
        READ_BV(T + 1);  READ_AV(T + 2, avA);  MFMA(avB);
    }
    // T = NT-4 (28): stage final tile
    WAITB("vmcnt(4)"); STAGE(NT - 1);
    READ_BV(NT - 4); READ_AV(NT - 3, avB); MFMA(avA);
    // T = NT-3 (29)
    WAITB("vmcnt(4)");
    READ_BV(NT - 3); READ_AV(NT - 2, avA); MFMA(avB);
    // T = NT-2 (30)
    WAITB("vmcnt(0)");
    READ_BV(NT - 2); READ_AV(NT - 1, avB); MFMA(avA);
    // T = NT-1 (31)
    READ_BV(NT - 1); MFMA(avB);

    __syncthreads();   // full drain before LDS reuse

    // Epilogue: acc -> LDS bf16 [256][256] -> coalesced 16B stores.
    // C/D layout (m89-verified): col = lane&15, row = (lane>>4)*4 + reg
    ushort_t* Cs = lds;
    const int orow = (l >> 4) << 2;
    const int ocol = l & 15;
    #pragma unroll
    for (int mi = 0; mi < 8; ++mi) {
        #pragma unroll
        for (int ni = 0; ni < 4; ++ni) {
            const int rl = (wr << 7) + (mi << 4) + orow;
            const int cl = (wc << 6) + (ni << 4) + ocol;
            #pragma unroll
            for (int r = 0; r < 4; ++r)
                Cs[(rl + r) * 256 + cl] = f2bf(acc[mi][ni][r]);
        }
    }
    __syncthreads();
    const size_t sliceBase = ((size_t)ks * NN + mBase) * 256;
    #pragma unroll
    for (int p = 0; p < 16; ++p) {
        const int idx16 = (p << 9) + tid;    // 0..8191 16B-chunks
        const int row   = idx16 >> 5;
        const int c16   = idx16 & 31;
        const uint4 v = *(const uint4*)(&Cs[(row << 8) + (c16 << 3)]);
        *(uint4*)(Yb + sliceBase + (size_t)row * 256 + (c16 << 3)) = v;
    }
}

// ---------------------------------------------------------------------------
// K4: fused reduce + postscale + next-level Bt build.
//   c<128:  y = s_j*Y + s_j^2*u   (hop);  Bt[c][j] = bf16(s_j * y)
//   c>=128: y = 0.5*(v + Y)       (walk); Bt[c][j] = bf16(rinv_j * y)
// Block tile: 64 j x 64 c. Bt written via LDS transpose. Bt==nullptr: skip
// transpose (L4). hop_out==nullptr: skip hop-half blocks entirely (L4).
__global__ __launch_bounds__(256) void reduce_prescale(const ushort_t* __restrict__ Yb,
    const float* __restrict__ u, const float* __restrict__ v,
    const float* __restrict__ s, const float* __restrict__ rinv,
    float* __restrict__ hop_out, float* __restrict__ walk_out,
    ushort_t* __restrict__ Bt)
{
    const int j0 = (blockIdx.x & 127) << 6;
    const int c0 = (blockIdx.x >> 7) << 6;
    const bool hop = (c0 < 128);
    if (hop && hop_out == nullptr) return;
    __shared__ ushort_t tT[64][66];
    const int cg = threadIdx.x & 15;     // 4-col group within the 64-col tile
    const int jr = threadIdx.x >> 4;     // row within 16-row stripe
    const size_t SL = (size_t)NN * 256;  // ushorts per K-split slice
    #pragma unroll
    for (int it = 0; it < 4; ++it) {
        const int jl = jr + (it << 4);
        const int j  = j0 + jl;
        const int c  = c0 + (cg << 2);
        const ushort_t* p = Yb + ((size_t)j << 8) + c;
        float e0 = 0.f, e1 = 0.f, e2 = 0.f, e3 = 0.f;
        #pragma unroll
        for (int kss = 0; kss < KS; ++kss) {
            const uint2 q = *(const uint2*)(p + kss * SL);
            e0 += bf2f(q.x & 0xffffu);
            e1 += __uint_as_float(q.x & 0xffff0000u);
            e2 += bf2f(q.y & 0xffffu);
            e3 += __uint_as_float(q.y & 0xffff0000u);
        }
        float4 o; float scale;
        if (hop) {
            const float si = s[j], si2 = si * si;
            const float4 uu = ((const float4*)u)[((size_t)j << 5) + (c >> 2)];
            o.x = si * e0 + si2 * uu.x;  o.y = si * e1 + si2 * uu.y;
            o.z = si * e2 + si2 * uu.z;  o.w = si * e3 + si2 * uu.w;
            ((float4*)hop_out)[((size_t)j << 5) + (c >> 2)] = o;
            scale = si;
        } else {
            const int cw = c - 128;
            const float4 vv = ((const float4*)v)[((size_t)j << 5) + (cw >> 2)];
            o.x = 0.5f * (vv.x + e0);  o.y = 0.5f * (vv.y + e1);
            o.z = 0.5f * (vv.z + e2);  o.w = 0.5f * (vv.w + e3);
            ((float4*)walk_out)[((size_t)j << 5) + (cw >> 2)] = o;
            scale = rinv[j];
        }
        if (Bt) {
            const int clb = cg << 2;
            tT[clb + 0][jl] = f2bf(scale * o.x);
            tT[clb + 1][jl] = f2bf(scale * o.y);
            tT[clb + 2][jl] = f2bf(scale * o.z);
            tT[clb + 3][jl] = f2bf(scale * o.w);
        }
    }
    if (Bt == nullptr) return;
    __syncthreads();
    const int tx = threadIdx.x & 63, ty = threadIdx.x >> 6;
    #pragma unroll
    for (int rr = 0; rr < 16; ++rr) {
        const int cl = ty + (rr << 2);
        Bt[((size_t)(c0 + cl) << 13) + j0 + tx] = tT[cl][tx];
    }
}

// ---------------------------------------------------------------------------
// K5: 6-way attention fusion. One wave per node; 2 k's per lane.
// The relu(X)@a[0:128] term is constant across the 6 slots -> cancels in softmax.
__global__ __launch_bounds__(256) void fuse_attn(const float* __restrict__ X,
    const float* __restrict__ hA, const float* __restrict__ hA2, const float* __restrict__ hA3,
    const float* __restrict__ px, const float* __restrict__ p2x, const float* __restrict__ p4x,
    const float* __restrict__ a, float* __restrict__ hp)
{
    const int w = threadIdx.x >> 6, l = threadIdx.x & 63;
    const size_t i = (size_t)blockIdx.x * 4 + w;
    const size_t base = i << 7;
    float f[6][2];
    float e[6] = {0.f, 0.f, 0.f, 0.f, 0.f, 0.f};
    #pragma unroll
    for (int h = 0; h < 2; ++h) {
        const int k = l + (h << 6);
        const float a2 = a[128 + k];
        const float x   = X[base + k];
        const float t1  = leaky(hA [base + k]);
        const float t2  = leaky(hA2[base + k]);
        const float t3  = leaky(hA3[base + k]);
        const float pk  = px [base + k];
        const float p2k = p2x[base + k];
        const float p4k = p4x[base + k];
        const float s1 = fabsf(x - pk);
        const float s2 = fabsf(pk - p2k);
        const float s3 = fabsf(p2k - p4k);
        f[0][h] = t1; f[1][h] = t2; f[2][h] = t3;
        f[3][h] = s1; f[4][h] = s2; f[5][h] = s3;
        e[0] += fmaxf(t1, 0.f) * a2;
        e[1] += fmaxf(t2, 0.f) * a2;
        e[2] += fmaxf(t3, 0.f) * a2;
        e[3] += s1 * a2;                 // |.| >= 0, relu is identity
        e[4] += s2 * a2;
        e[5] += s3 * a2;
    }
    #pragma unroll
    for (int ss = 0; ss < 6; ++ss) {
        #pragma unroll
        for (int off = 32; off; off >>= 1) e[ss] += __shfl_xor(e[ss], off);
    }
    float mx = e[0];
    #pragma unroll
    for (int ss = 1; ss < 6; ++ss) mx = fmaxf(mx, e[ss]);
    float at[6], sum = 0.f;
    #pragma unroll
    for (int ss = 0; ss < 6; ++ss) { at[ss] = expf(e[ss] - mx); sum += at[ss]; }
    const float inv = 1.f / (6.f * sum);
    #pragma unroll
    for (int h = 0; h < 2; ++h) {
        float o = 0.f;
        #pragma unroll
        for (int ss = 0; ss < 6; ++ss) o += at[ss] * f[ss][h];
        hp[base + l + (h << 6)] = o * inv;
    }
}

// ---------------------------------------------------------------------------
// K6: out = leaky(Hm @ W^T + b), f32. W staged in LDS (stride 140).
__global__ __launch_bounds__(256) void mlp(const float* __restrict__ Hm,
    const float* __restrict__ W, const float* __restrict__ b, float* __restrict__ out)
{
    __shared__ float Ws[128 * 140];
    __shared__ float Hs[16 * 140];
    const int node0 = blockIdx.x << 4;
    for (int rr = 0; rr < 64; ++rr) {
        const int idx = rr * 256 + threadIdx.x;
        Ws[(idx >> 7) * 140 + (idx & 127)] = W[idx];
    }
    #pragma unroll
    for (int rr = 0; rr < 8; ++rr) {
        const int idx = rr * 256 + threadIdx.x;
        Hs[(idx >> 7) * 140 + (idx & 127)] = Hm[((size_t)node0 << 7) + idx];
    }
    __syncthreads();
    const int c = threadIdx.x & 15;
    const int n = threadIdx.x >> 4;
    float acc[8] = {};
    for (int k4 = 0; k4 < 32; ++k4) {
        const float4 h4 = *(const float4*)(&Hs[n * 140 + (k4 << 2)]);
        #pragma unroll
        for (int r = 0; r < 8; ++r) {
            const float4 w4 = *(const float4*)(&Ws[(c + (r << 4)) * 140 + (k4 << 2)]);
            acc[r] += h4.x * w4.x + h4.y * w4.y + h4.z * w4.z + h4.w * w4.w;
        }
    }
    const size_t obase = ((size_t)(node0 + n)) << 7;
    #pragma unroll
    for (int r = 0; r < 8; ++r) {
        const int o = c + (r << 4);
        out[obase + o] = leaky(acc[r] + b[o]);
    }
}

// ---------------------------------------------------------------------------
extern "C" void kernel_launch(void* const* d_in, const int* in_sizes, int n_in,
                              void* d_out, int out_size, void* d_ws, size_t ws_size,
                              hipStream_t stream)
{
    const float* X   = (const float*)d_in[0];
    const float* adj = (const float*)d_in[1];
    const float* W1  = (const float*)d_in[2];
    const float* b1  = (const float*)d_in[3];
    const float* W2  = (const float*)d_in[4];
    const float* b2  = (const float*)d_in[5];
    const float* a   = (const float*)d_in[6];
    float* out = (float*)d_out;

    // Workspace layout (~192.1 MB total)
    char* ws = (char*)d_ws;
    ushort_t* adjb = (ushort_t*)ws;                        // 128 MB
    ushort_t* Bt   = (ushort_t*)(ws + 134217728ull);       //   4 MB
    ushort_t* Yb   = (ushort_t*)(ws + 138412032ull);       //  32 MB (KS=8 bf16 partials)
    float* hA  = (float*)(ws + 171966464ull);              //   4 MB each below
    float* hA2 = hA  + 1048576;
    float* hA3 = hA2 + 1048576;
    float* px  = hA3 + 1048576;
    float* p2x = px  + 1048576;
    float* p3x = p2x + 1048576;
    float* p4x = p3x + 1048576;
    float* sbuf  = p4x + 1048576;                          // 32 KB
    float* rinvb = sbuf + 8192;                            // 32 KB
    float* hp   = (float*)Bt;   // overlay: Bt dead after L4 GEMM
    float* out1 = (float*)Yb;   // overlay: Yb dead after L4 reduce

    conv_rowsum<<<8192, 256, 0, stream>>>(adj, adjb, sbuf, rinvb);

    // Level 1: Bt from (X, X)
    prescale<<<512, 256, 0, stream>>>(X, X, sbuf, rinvb, Bt);
    gemm_adj<<<256, 512, 0, stream>>>(adjb, Bt, Yb);
    reduce_prescale<<<512, 256, 0, stream>>>(Yb, X, X, sbuf, rinvb,
                                             hA, px, Bt);        // -> Bt for L2
    // Level 2
    gemm_adj<<<256, 512, 0, stream>>>(adjb, Bt, Yb);
    reduce_prescale<<<512, 256, 0, stream>>>(Yb, hA, px, sbuf, rinvb,
                                             hA2, p2x, Bt);      // -> Bt for L3
    // Level 3
    gemm_adj<<<256, 512, 0, stream>>>(adjb, Bt, Yb);
    reduce_prescale<<<512, 256, 0, stream>>>(Yb, hA2, p2x, sbuf, rinvb,
                                             hA3, p3x, Bt);      // -> Bt for L4
    // Level 4 (walk only consumed; hop half computed but discarded)
    gemm_adj<<<256, 512, 0, stream>>>(adjb, Bt, Yb);
    reduce_prescale<<<512, 256, 0, stream>>>(Yb, nullptr, p3x, sbuf, rinvb,
                                             nullptr, p4x, nullptr);

    fuse_attn<<<2048, 256, 0, stream>>>(X, hA, hA2, hA3, px, p2x, p4x, a, hp);
    mlp<<<512, 256, 0, stream>>>(hp, W1, b1, out1);
    mlp<<<512, 256, 0, stream>>>(out1, W2, b2, out);
}